// Round 9
// baseline (251.222 us; speedup 1.0000x reference)
//
#include <hip/hip_runtime.h>
#include <cstdint>
#include <cmath>

#define T_SEQ 2048
#define NBATCH 8
#define DM 1024
#define DH 512
#define MROWS (NBATCH * T_SEQ)   // 16384
#define NC 16                    // chunks per batch
#define CL 128                   // chunk length

typedef short s8v __attribute__((ext_vector_type(8)));
typedef float f32x4 __attribute__((ext_vector_type(4)));

typedef unsigned int __attribute__((address_space(1))) uint_g;
typedef unsigned int __attribute__((address_space(3))) uint_l;

#define QKSCALE 0.044194173824159216f   // 1/sqrt(512)

__device__ __forceinline__ float b2f(unsigned short s) {
    union { unsigned u; float f; } c; c.u = ((unsigned)s) << 16; return c.f;
}
__device__ __forceinline__ unsigned short f2b(float f) {
    union { float f; unsigned u; } c; c.f = f;
    unsigned r = c.u + 0x7fffu + ((c.u >> 16) & 1u);
    return (unsigned short)(r >> 16);
}
__device__ __forceinline__ void gld_lds16(const void* g, void* l) {
    __builtin_amdgcn_global_load_lds((const uint_g*)g, (uint_l*)l, 16, 0, 0);
}

#define WAITV(N) asm volatile("s_waitcnt vmcnt(" #N ")" ::: "memory")
#define BARSYNC() do { asm volatile("" ::: "memory"); __builtin_amdgcn_s_barrier(); asm volatile("" ::: "memory"); } while (0)

// ---------------- RMSNorm + zi/zf + fused weight conversion ----------------
__global__ __launch_bounds__(256) void norm_kernel(
    const float* __restrict__ x, const float* __restrict__ nw,
    const float* __restrict__ wi, const float* __restrict__ wf,
    const float* __restrict__ wib, const float* __restrict__ wfb,
    unsigned short* __restrict__ normed, float* __restrict__ zi, float* __restrict__ zf,
    const float* __restrict__ Wq, const float* __restrict__ Wk,
    const float* __restrict__ Wo, const float* __restrict__ Wv,
    const float* __restrict__ Wout,
    unsigned short* __restrict__ Wcat1, unsigned short* __restrict__ WvB,
    unsigned short* __restrict__ Woutb)
{
    int t = blockIdx.x, tid = threadIdx.x;
    float4 xv = ((const float4*)(x + (size_t)t * DM))[tid];
    float ss = xv.x * xv.x + xv.y * xv.y + xv.z * xv.z + xv.w * xv.w;
#pragma unroll
    for (int m = 1; m < 64; m <<= 1) ss += __shfl_xor(ss, m, 64);
    __shared__ float sred[4];
    __shared__ float sred2[8];
    if ((tid & 63) == 0) sred[tid >> 6] = ss;
    __syncthreads();
    ss = sred[0] + sred[1] + sred[2] + sred[3];
    float rstd = rsqrtf(ss * (1.0f / DM) + 1e-6f);
    float4 nwv = ((const float4*)nw)[tid];
    float n0 = xv.x * rstd * nwv.x, n1 = xv.y * rstd * nwv.y;
    float n2 = xv.z * rstd * nwv.z, n3 = xv.w * rstd * nwv.w;
    ushort4 pk;
    pk.x = f2b(n0); pk.y = f2b(n1); pk.z = f2b(n2); pk.w = f2b(n3);
    ((ushort4*)(normed + (size_t)t * DM))[tid] = pk;
    float4 wiv = ((const float4*)wi)[tid];
    float4 wfv = ((const float4*)wf)[tid];
    float pzi = n0 * wiv.x + n1 * wiv.y + n2 * wiv.z + n3 * wiv.w;
    float pzf = n0 * wfv.x + n1 * wfv.y + n2 * wfv.z + n3 * wfv.w;
#pragma unroll
    for (int m = 1; m < 64; m <<= 1) {
        pzi += __shfl_xor(pzi, m, 64);
        pzf += __shfl_xor(pzf, m, 64);
    }
    if ((tid & 63) == 0) { sred2[tid >> 6] = pzi; sred2[4 + (tid >> 6)] = pzf; }
    __syncthreads();
    if (tid == 0) {
        zi[t] = sred2[0] + sred2[1] + sred2[2] + sred2[3] + wib[0];
        zf[t] = sred2[4] + sred2[5] + sred2[6] + sred2[7] + wfb[0];
    }
    // ---- fused weight conversion ----
    if (tid < 160) {
        int idx = blockIdx.x * 160 + tid;
        if (idx < 1572864) {
            int nrow = idx >> 10;
            float v;
            if      (nrow < 512)  v = Wq[idx];
            else if (nrow < 1024) v = Wk[idx - 512 * 1024];
            else                  v = Wo[idx - 1024 * 1024];
            Wcat1[idx] = f2b(v);
        } else if (idx < 2097152) {
            int j = idx - 1572864;
            WvB[j] = f2b(Wv[j]);
        } else {
            int j = idx - 2097152;
            Woutb[j] = f2b(Wout[j]);
        }
    }
}

// ---------------- merged QKO + V projection + mscan2 (blocks 2048+) ------
__global__ __launch_bounds__(256, 4) void gemm_qkv_ms(
    const unsigned short* __restrict__ normed, const unsigned short* __restrict__ Wcat1,
    const unsigned short* __restrict__ WvB, int K,
    unsigned short* __restrict__ qko, const float* __restrict__ bo,
    unsigned short* __restrict__ vout,
    const float* __restrict__ zi, const float* __restrict__ zf,
    float* __restrict__ u, float* __restrict__ a)
{
    __shared__ unsigned short As[128 * 64];
    __shared__ unsigned short Bs[128 * 64];
    __shared__ float wt[4];
    int tid = threadIdx.x;

    if (blockIdx.x >= 2048) {
        // ---- mscan2 body ----
        int b = blockIdx.x - 2048, lane = tid & 63, wid = tid >> 6;
        size_t base = (size_t)b * T_SEQ + tid * 8;
        float z_f[8], z_i[8];
        *(float4*)&z_f[0] = *(const float4*)&zf[base];
        *(float4*)&z_f[4] = *(const float4*)&zf[base + 4];
        *(float4*)&z_i[0] = *(const float4*)&zi[base];
        *(float4*)&z_i[4] = *(const float4*)&zi[base + 4];
        float c8[8]; float run = 0.0f;
#pragma unroll
        for (int i = 0; i < 8; ++i) { run += z_f[i]; c8[i] = run; }
        float v = run;
#pragma unroll
        for (int d = 1; d < 64; d <<= 1) {
            float o = __shfl_up(v, d, 64);
            if (lane >= d) v += o;
        }
        if (lane == 63) wt[wid] = v;
        __syncthreads();
        float woff = 0.0f;
        for (int j = 0; j < wid; ++j) woff += wt[j];
        float excl = __shfl_up(v, 1, 64);
        if (lane == 0) excl = 0.0f;
        float pre = woff + excl;
        float uu[8];
#pragma unroll
        for (int i = 0; i < 8; ++i) uu[i] = z_i[i] - (pre + c8[i]);
        *(float4*)&u[base] = *(float4*)&uu[0];
        *(float4*)&u[base + 4] = *(float4*)&uu[4];
        __syncthreads();
        float m8[8]; float rm = -INFINITY;
#pragma unroll
        for (int i = 0; i < 8; ++i) { rm = fmaxf(rm, uu[i]); m8[i] = rm; }
        float mv = rm;
#pragma unroll
        for (int d = 1; d < 64; d <<= 1) {
            float o = __shfl_up(mv, d, 64);
            if (lane >= d) mv = fmaxf(mv, o);
        }
        if (lane == 63) wt[wid] = mv;
        __syncthreads();
        float moff = -INFINITY;
        for (int j = 0; j < wid; ++j) moff = fmaxf(moff, wt[j]);
        float mexcl = __shfl_up(mv, 1, 64);
        if (lane == 0) mexcl = -INFINITY;
        float mpre = fmaxf(moff, mexcl);
        float aa[8];
#pragma unroll
        for (int i = 0; i < 8; ++i) aa[i] = fmaxf(mpre, m8[i]);
        *(float4*)&a[base] = *(float4*)&aa[0];
        *(float4*)&a[base + 4] = *(float4*)&aa[4];
        return;
    }

    // ---- GEMM body ----
    int l = tid & 63, w = tid >> 6;
    int wg = (blockIdx.x & 7) * 256 + (blockIdx.x >> 3);   // bijective, 2048 blocks
    int job = (wg >= 1536) ? 1 : 0;
    const unsigned short* A;
    const unsigned short* Bw;
    int bm, bn;
    if (job == 0) { A = normed; Bw = Wcat1; bn = wg % 12; bm = wg / 12; }
    else          { int w2 = wg - 1536; A = WvB; Bw = normed; bm = w2 & 3; bn = w2 >> 2; }
    int wr = w >> 1, wc = w & 1;
    f32x4 acc[4][4] = {};
    const size_t abase = (size_t)(bm * 128) * K;
    const size_t bbase = (size_t)(bn * 128) * K;

    for (int ks = 0; ks < K; ks += 64) {
        __syncthreads();
#pragma unroll
        for (int i = 0; i < 4; ++i) {
            int off = (i * 256 + tid) * 8;
            int row = off >> 6, kc = off & 63;
            int kcs = kc ^ ((row & 7) << 3);
            gld_lds16(A + abase + (size_t)row * K + ks + kcs, &As[off]);
            gld_lds16(Bw + bbase + (size_t)row * K + ks + kcs, &Bs[off]);
        }
        __syncthreads();
#pragma unroll
        for (int kk = 0; kk < 2; ++kk) {
            int cbo = kk * 32 + (l >> 4) * 8;
            s8v af[4], bfv[4];
#pragma unroll
            for (int m = 0; m < 4; ++m) {
                int row = wr * 64 + m * 16 + (l & 15);
                af[m] = *(const s8v*)&As[row * 64 + (cbo ^ ((row & 7) << 3))];
            }
#pragma unroll
            for (int n = 0; n < 4; ++n) {
                int row = wc * 64 + n * 16 + (l & 15);
                bfv[n] = *(const s8v*)&Bs[row * 64 + (cbo ^ ((row & 7) << 3))];
            }
#pragma unroll
            for (int m = 0; m < 4; ++m)
#pragma unroll
                for (int n = 0; n < 4; ++n)
                    acc[m][n] = __builtin_amdgcn_mfma_f32_16x16x32_bf16(af[m], bfv[n], acc[m][n], 0, 0, 0);
        }
    }

    if (job == 0) {
#pragma unroll
        for (int m = 0; m < 4; ++m) {
#pragma unroll
            for (int n = 0; n < 4; ++n) {
                int col = bn * 128 + wc * 64 + n * 16 + (l & 15);
#pragma unroll
                for (int r = 0; r < 4; ++r) {
                    int row = bm * 128 + wr * 64 + m * 16 + (l >> 4) * 4 + r;
                    float v = acc[m][n][r];
                    if (col < 1024) v *= QKSCALE;
                    else {
                        float s = v + bo[col - 1024];
                        v = 1.0f / (1.0f + expf(-s));
                    }
                    qko[(size_t)row * 1536 + col] = f2b(v);
                }
            }
        }
    } else {
#pragma unroll
        for (int m = 0; m < 4; ++m) {
#pragma unroll
            for (int n = 0; n < 4; ++n) {
                int col = bn * 128 + wc * 64 + n * 16 + (l & 15);
#pragma unroll
                for (int r = 0; r < 4; ++r) {
                    int row = bm * 128 + wr * 64 + m * 16 + (l >> 4) * 4 + r;
                    vout[(size_t)row * MROWS + col] = f2b(acc[m][n][r]);
                }
            }
        }
    }
}

// ---------------- 128x128 bf16 MFMA GEMM (output projection) -------------
template <int EPI, int ORD>
__global__ __launch_bounds__(256, 4) void gemm_bt(
    const unsigned short* __restrict__ A, const unsigned short* __restrict__ Bw,
    int M, int N, int K, int ldo,
    unsigned short* __restrict__ outb, const float* __restrict__ bo,
    float* __restrict__ outf, const float* __restrict__ xres)
{
    __shared__ unsigned short As[128 * 64];
    __shared__ unsigned short Bs[128 * 64];
    int tid = threadIdx.x;
    int l = tid & 63, w = tid >> 6;
    int cpx = gridDim.x >> 3;
    int wg = (blockIdx.x & 7) * cpx + (blockIdx.x >> 3);
    int mb = M >> 7;
    int nb = N >> 7;
    int bm, bn;
    if (ORD == 0) { bm = wg % mb; bn = wg / mb; }
    else          { bn = wg % nb; bm = wg / nb; }
    int wr = w >> 1, wc = w & 1;
    f32x4 acc[4][4] = {};
    const size_t abase = (size_t)(bm * 128) * K;
    const size_t bbase = (size_t)(bn * 128) * K;

    for (int ks = 0; ks < K; ks += 64) {
        __syncthreads();
#pragma unroll
        for (int i = 0; i < 4; ++i) {
            int off = (i * 256 + tid) * 8;
            int row = off >> 6, kc = off & 63;
            int kcs = kc ^ ((row & 7) << 3);
            gld_lds16(A + abase + (size_t)row * K + ks + kcs, &As[off]);
            gld_lds16(Bw + bbase + (size_t)row * K + ks + kcs, &Bs[off]);
        }
        __syncthreads();
#pragma unroll
        for (int kk = 0; kk < 2; ++kk) {
            int cbo = kk * 32 + (l >> 4) * 8;
            s8v af[4], bfv[4];
#pragma unroll
            for (int m = 0; m < 4; ++m) {
                int row = wr * 64 + m * 16 + (l & 15);
                af[m] = *(const s8v*)&As[row * 64 + (cbo ^ ((row & 7) << 3))];
            }
#pragma unroll
            for (int n = 0; n < 4; ++n) {
                int row = wc * 64 + n * 16 + (l & 15);
                bfv[n] = *(const s8v*)&Bs[row * 64 + (cbo ^ ((row & 7) << 3))];
            }
#pragma unroll
            for (int m = 0; m < 4; ++m)
#pragma unroll
                for (int n = 0; n < 4; ++n)
                    acc[m][n] = __builtin_amdgcn_mfma_f32_16x16x32_bf16(af[m], bfv[n], acc[m][n], 0, 0, 0);
        }
    }

#pragma unroll
    for (int m = 0; m < 4; ++m) {
#pragma unroll
        for (int n = 0; n < 4; ++n) {
            int col = bn * 128 + wc * 64 + n * 16 + (l & 15);
#pragma unroll
            for (int r = 0; r < 4; ++r) {
                int row = bm * 128 + wr * 64 + m * 16 + (l >> 4) * 4 + r;
                float v = acc[m][n][r];
                if (EPI == 3) {
                    outb[(size_t)row * ldo + col] = f2b(v);
                } else {
                    size_t idx = (size_t)row * ldo + col;
                    outf[idx] = xres[idx] + v;
                }
            }
        }
    }
}

// ---------------- fusedA: phaseA (blocks 0..255) + kwprep2 (256..1279) ----
// R6 measured-best body (17.9 KB union -> 8 blocks/CU capacity).
__global__ __launch_bounds__(256) void fusedA_kernel(
    const unsigned short* __restrict__ qko,
    const float* __restrict__ u, const float* __restrict__ a,
    unsigned short* __restrict__ stb, float* __restrict__ rowsum,
    unsigned short* __restrict__ kw, float* __restrict__ P, float* __restrict__ aE)
{
    __shared__ char smem[17920];
    int bid = blockIdx.x, tid = threadIdx.x;

    if (bid < 256) {
        // ---- phaseA: St[t][j] = exp(u_j - a_t)*(q_t.k_j), j<=t ----
        unsigned short* Qs = (unsigned short*)smem;            // 64*32
        unsigned short* Ks = (unsigned short*)(smem + 4096);   // 128*32
        int b = bid & 7, c = (bid >> 3) & 15, th = bid >> 7;
        int l = tid & 63, wv = tid >> 6;
        size_t cb = (size_t)b * T_SEQ + c * CL;
        f32x4 acc[8] = {};
        for (int ks = 0; ks < 512; ks += 32) {
            __syncthreads();
            {
                int p = tid;
                int row = p >> 2, kc = (p & 3) * 8;
                gld_lds16(qko + (cb + th * 64 + row) * 1536 + ks + kc, &Qs[p * 8]);
#pragma unroll
                for (int rI = 0; rI < 2; ++rI) {
                    int pp = rI * 256 + tid;
                    int rw = pp >> 2, kk = (pp & 3) * 8;
                    gld_lds16(qko + (cb + rw) * 1536 + 512 + ks + kk, &Ks[pp * 8]);
                }
            }
            __syncthreads();
            s8v af = *(const s8v*)&Qs[(wv * 16 + (l & 15)) * 32 + (l >> 4) * 8];
#pragma unroll
            for (int n = 0; n < 8; ++n) {
                s8v bf = *(const s8v*)&Ks[(n * 16 + (l & 15)) * 32 + (l >> 4) * 8];
                acc[n] = __builtin_amdgcn_mfma_f32_16x16x32_bf16(af, bf, acc[n], 0, 0, 0);
            }
        }
        float rs[4] = {0.f, 0.f, 0.f, 0.f};
        size_t stbase = (size_t)(b * NC + c) * (CL * CL);
#pragma unroll
        for (int e = 0; e < 4; ++e) {
            int tl = th * 64 + wv * 16 + (l >> 4) * 4 + e;
            float a_t = a[cb + tl];
#pragma unroll
            for (int n = 0; n < 8; ++n) {
                int j = n * 16 + (l & 15);
                float val = (j <= tl) ? acc[n][e] * expf(u[cb + j] - a_t) : 0.0f;
                rs[e] += val;
                stb[stbase + (size_t)tl * CL + j] = f2b(val);
            }
        }
#pragma unroll
        for (int e = 0; e < 4; ++e) {
#pragma unroll
            for (int m = 1; m < 16; m <<= 1) rs[e] += __shfl_xor(rs[e], m, 64);
        }
        if ((l & 15) == 0) {
#pragma unroll
            for (int e = 0; e < 4; ++e)
                rowsum[cb + th * 64 + wv * 16 + (l >> 4) * 4 + e] = rs[e];
        }
    } else {
        // ---- kwprep2: transpose k + scale; P row-sums ----
        unsigned short (*T)[136] = (unsigned short(*)[136])smem;   // 64*136
        float* w_l = (float*)(smem + 17408);                       // CL floats
        int kb = bid - 256;
        int b = kb & 7, c = (kb >> 3) & 15, stt = kb >> 7;   // stt: 0..7
        int s0 = stt * 64;
        size_t cb = (size_t)b * T_SEQ + c * CL;
        float a_e = a[cb + CL - 1];
        if (tid < CL) w_l[tid] = expf(u[cb + tid] - a_e);
        if (tid == 0 && stt == 0) aE[b * NC + c] = a_e;
#pragma unroll
        for (int it = 0; it < 4; ++it) {
            int flat = it * 256 + tid;          // 0..1023
            int t = flat >> 3, g = flat & 7;
            s8v v = *(const s8v*)&qko[(cb + t) * 1536 + 512 + s0 + g * 8];
#pragma unroll
            for (int e = 0; e < 8; ++e) T[g * 8 + e][t] = (unsigned short)v[e];
        }
        __syncthreads();
        int s = tid >> 2, tg = tid & 3;
        float psum = 0.0f;
#pragma unroll
        for (int j = 0; j < 4; ++j) {
            int t0 = tg * 32 + j * 8;
            s8v kv = *(const s8v*)&T[s][t0];
            s8v kwv;
#pragma unroll
            for (int e = 0; e < 8; ++e) {
                float f = b2f((unsigned short)kv[e]) * w_l[t0 + e];
                kwv[e] = (short)f2b(f);
                psum += f;
            }
            *(s8v*)&kw[(size_t)(s0 + s) * MROWS + cb + t0] = kwv;
        }
        psum += __shfl_xor(psum, 1, 64);
        psum += __shfl_xor(psum, 2, 64);
        if (tg == 0) P[(size_t)(b * NC + c) * 512 + s0 + s] = psum;
    }
}

// ---------------- cscan3: C checkpoints + fused denom/nhscan epilogue ----
__global__ __launch_bounds__(256, 2) void cscan3_kernel(
    const unsigned short* __restrict__ kvT, const unsigned short* __restrict__ kw,
    const float* __restrict__ aE, unsigned short* __restrict__ chk,
    const unsigned short* __restrict__ qko, const float* __restrict__ P,
    const float* __restrict__ a, const float* __restrict__ rowsum,
    float* __restrict__ rdnm)
{
    __shared__ unsigned short Vs[2][64 * 128];
    __shared__ unsigned short Ks[2][64 * 128];
    int bid = blockIdx.x;
    int b = bid & 7, rt = (bid >> 3) & 7, st = bid >> 6;   // 8 x 8 x 8
    int r0 = rt * 64, s0 = st * 64;
    int tid = threadIdx.x, l = tid & 63;
    int w = tid >> 6, wr = w >> 1, wc = w & 1;
    size_t tb = (size_t)b * T_SEQ;
    int srow = tid >> 4, sg = tid & 15;
    f32x4 acc[2][2] = {};
    float a_prev = 0.0f;

#define CSTAGE(c, buf) do { \
        size_t cb_ = tb + (size_t)(c) * CL; \
        _Pragma("unroll") \
        for (int i = 0; i < 4; ++i) { \
            int row_ = i * 16 + srow; \
            int gs_ = sg ^ (row_ & 7); \
            gld_lds16(kvT + (size_t)(512 + r0 + row_) * MROWS + cb_ + gs_ * 8, \
                      &Vs[buf][(i * 256 + tid) * 8]); \
        } \
        _Pragma("unroll") \
        for (int i = 0; i < 4; ++i) { \
            int row_ = i * 16 + srow; \
            int gs_ = sg ^ (row_ & 7); \
            gld_lds16(kw + (size_t)(s0 + row_) * MROWS + cb_ + gs_ * 8, \
                      &Ks[buf][(i * 256 + tid) * 8]); \
        } } while (0)

    CSTAGE(0, 0);
    for (int c = 0; c < NC; ++c) {
        int cur = c & 1;
        if (c + 1 < NC) { CSTAGE(c + 1, cur ^ 1); WAITV(8); }
        else            { WAITV(0); }
        BARSYNC();
        float a_e = aE[b * NC + c];
        if (c > 0) {
            unsigned short* slot = chk + (size_t)(b * (NC - 1) + (c - 1)) * (512 * 512);
#pragma unroll
            for (int m = 0; m < 2; ++m)
#pragma unroll
                for (int n = 0; n < 2; ++n)
#pragma unroll
                    for (int e = 0; e < 4; ++e) {
                        int r = r0 + wr * 32 + m * 16 + (l >> 4) * 4 + e;
                        int s = s0 + wc * 32 + n * 16 + (l & 15);
                        slot[r * 512 + s] = f2b(acc[m][n][e]);
                    }
            float gam = expf(a_prev - a_e);
#pragma unroll
            for (int m = 0; m < 2; ++m)
#pragma unroll
                for (int n = 0; n < 2; ++n)
#pragma unroll
                    for (int e = 0; e < 4; ++e) acc[m][n][e] *= gam;
        }
#pragma unroll
        for (int ks = 0; ks < 4; ++ks) {
            s8v vf[2], kf[2];
#pragma unroll
            for (int m = 0; m < 2; ++m) {
                int row = wr * 32 + m * 16 + (l & 15);
                int gf = ks * 4 + (l >> 4);
                vf[m] = *(const s8v*)&Vs[cur][row * 128 + ((gf ^ (row & 7)) << 3)];
            }
#pragma unroll
            for (int n = 0; n < 2; ++n) {
                int row = wc * 32 + n * 16 + (l & 15);
                int gf = ks * 4 + (l >> 4);
                kf[n] = *(const s8v*)&Ks[cur][row * 128 + ((gf ^ (row & 7)) << 3)];
            }
#pragma unroll
            for (int m = 0; m < 2; ++m)
#pragma unroll
                for (int n = 0; n < 2; ++n)
                    acc[m][n] = __builtin_amdgcn_mfma_f32_16x16x32_bf16(vf[m], kf[n], acc[m][n], 0, 0, 0);
        }
        a_prev = a_e;
        BARSYNC();
    }
#undef CSTAGE

    // ---- fused denom (nhscan inline): 32 t's per block, 8 per wave ----
    {
        int wv = tid >> 6;
        int t0 = bid * 32 + wv * 8;
        int bt = t0 >> 11, ct = (t0 & 2047) >> 7;
        float nh[8] = {0, 0, 0, 0, 0, 0, 0, 0};
        float aprev = 0.0f;
        for (int cp = 0; cp < ct; ++cp) {
            float ae = aE[bt * NC + cp];
            float gam = (cp == 0) ? 0.0f : expf(aprev - ae);
            const float* Pp = P + (size_t)(bt * NC + cp) * 512 + l * 8;
            float4 p0 = *(const float4*)Pp;
            float4 p1 = *(const float4*)(Pp + 4);
#pragma unroll
            for (int e = 0; e < 8; ++e) nh[e] *= gam;
            nh[0] += p0.x; nh[1] += p0.y; nh[2] += p0.z; nh[3] += p0.w;
            nh[4] += p1.x; nh[5] += p1.y; nh[6] += p1.z; nh[7] += p1.w;
            aprev = ae;
        }
        float aeprev = (ct > 0) ? aE[bt * NC + ct - 1] : 0.0f;
        for (int tt = 0; tt < 8; ++tt) {
            int tc = t0 + tt;
            s8v qv = *(const s8v*)(qko + (size_t)tc * 1536 + l * 8);
            float nq = 0.0f;
#pragma unroll
            for (int e = 0; e < 8; ++e) nq += b2f((unsigned short)qv[e]) * nh[e];
#pragma unroll
            for (int m = 1; m < 64; m <<= 1) nq += __shfl_xor(nq, m, 64);
            if (l == 0) {
                float beta = (ct == 0) ? 0.0f : expf(aeprev - a[tc]);
                rdnm[tc] = 1.0f / fmaxf(fabsf(beta * nq + rowsum[tc]), 1.0f);
            }
        }
    }
}

// ---------------- hout4: G = beta*(Q.Cchk^T) + St.V ; h = o*G*rdnm --------
// hout2 split 256 -> 512 blocks (rq in 0..3, 128 r-rows each): 2 blocks/CU
// so barrier/stage stalls of one block overlap the other's MFMA. Stage
// [128 r][64 k] = 16 KB/buf, dbuf, counted WAITV(2) (2 loads/thread/step).
// Swizzle geometry identical to hout2 (rule 21, 2 lanes/bank on reads).
__global__ __launch_bounds__(512) void hout4_kernel(
    const unsigned short* __restrict__ qko, const unsigned short* __restrict__ kvT,
    const unsigned short* __restrict__ st, const unsigned short* __restrict__ chk,
    const float* __restrict__ a, const float* __restrict__ aE,
    const float* __restrict__ rdnm, unsigned short* __restrict__ g)
{
    __shared__ unsigned short Bsh[2][128 * 64];
    int bid = blockIdx.x;
    int b = bid & 7, cc = bid >> 3;          // cc: 0..63
    int c = cc >> 2, rq = cc & 3;
    int tid = threadIdx.x, l = tid & 63, wv = tid >> 6;
    int mq = wv & 3, rg = wv >> 2;           // rg: 0..1 (64 r-rows each)
    int R0 = rq * 128;
    size_t cb = (size_t)b * T_SEQ + c * CL;
    f32x4 acc[2][4] = {};

    int srow7 = tid >> 3;        // 0..63 (row within 64-row group)
    int sgc = tid & 7;

    if (c > 0) {
        const unsigned short* slot = chk + (size_t)(b * (NC - 1) + (c - 1)) * (512 * 512);
#define HSTG_C(ksb, buf) do { \
        _Pragma("unroll") \
        for (int i = 0; i < 2; ++i) { \
            int row_ = i * 64 + srow7; \
            int gs_ = sgc ^ (row_ & 7); \
            gld_lds16(slot + (size_t)(R0 + row_) * 512 + (ksb) * 64 + gs_ * 8, \
                      &Bsh[buf][(i * 512 + tid) * 8]); \
        } } while (0)
        HSTG_C(0, 0);
        for (int s = 0; s < 8; ++s) {
            int cur = s & 1;
            if (s + 1 < 8) { HSTG_C(s + 1, cur ^ 1); WAITV(2); }
            else           { WAITV(0); }
            BARSYNC();
#pragma unroll
            for (int kk = 0; kk < 2; ++kk) {
                s8v aq[2];
#pragma unroll
                for (int mf = 0; mf < 2; ++mf)
                    aq[mf] = *(const s8v*)&qko[(cb + mq * 32 + mf * 16 + (l & 15)) * 1536 + s * 64 + kk * 32 + (l >> 4) * 8];
#pragma unroll
                for (int n = 0; n < 4; ++n) {
                    int row = rg * 64 + n * 16 + (l & 15);
                    int gr = (kk * 4 + (l >> 4)) ^ (row & 7);
                    s8v bc = *(const s8v*)&Bsh[cur][row * 64 + gr * 8];
                    acc[0][n] = __builtin_amdgcn_mfma_f32_16x16x32_bf16(aq[0], bc, acc[0][n], 0, 0, 0);
                    acc[1][n] = __builtin_amdgcn_mfma_f32_16x16x32_bf16(aq[1], bc, acc[1][n], 0, 0, 0);
                }
            }
            BARSYNC();
        }
#undef HSTG_C
        float aprev = aE[b * NC + c - 1];
#pragma unroll
        for (int mf = 0; mf < 2; ++mf)
#pragma unroll
            for (int e = 0; e < 4; ++e) {
                int t = mq * 32 + mf * 16 + (l >> 4) * 4 + e;
                float bta = expf(aprev - a[cb + t]);
#pragma unroll
                for (int n = 0; n < 4; ++n) acc[mf][n][e] *= bta;
            }
    }

    // ---- St.V phase: V tile [128 r][64 t-cols], 2 steps ----
    const unsigned short* stp = st + (size_t)(b * NC + c) * (CL * CL);
#define HSTG_V(vsb, buf) do { \
        _Pragma("unroll") \
        for (int i = 0; i < 2; ++i) { \
            int row_ = i * 64 + srow7; \
            int gs_ = sgc ^ (row_ & 7); \
            gld_lds16(kvT + (size_t)(512 + R0 + row_) * MROWS + cb + (vsb) * 64 + gs_ * 8, \
                      &Bsh[buf][(i * 512 + tid) * 8]); \
        } } while (0)
    HSTG_V(0, 0);
    for (int s = 0; s < 2; ++s) {
        if (s + 1 < 2) { HSTG_V(1, 1); WAITV(2); }
        else           { WAITV(0); }
        BARSYNC();
#pragma unroll
        for (int kk = 0; kk < 2; ++kk) {
            s8v aq[2];
#pragma unroll
            for (int mf = 0; mf < 2; ++mf)
                aq[mf] = *(const s8v*)&stp[(size_t)(mq * 32 + mf * 16 + (l & 15)) * CL + s * 64 + kk * 32 + (l >> 4) * 8];
#pragma unroll
            for (int n = 0; n < 4; ++n) {
                int row = rg * 64 + n * 16 + (l & 15);
                int gr = (kk * 4 + (l >> 4)) ^ (row & 7);
                s8v bv = *(const s8v*)&Bsh[s][row * 64 + gr * 8];
                acc[0][n] = __builtin_amdgcn_mfma_f32_16x16x32_bf16(aq[0], bv, acc[0][n], 0, 0, 0);
                acc[1][n] = __builtin_amdgcn_mfma_f32_16x16x32_bf16(aq[1], bv, acc[1][n], 0, 0, 0);
            }
        }
        BARSYNC();
    }
#undef HSTG_V

#pragma unroll
    for (int mf = 0; mf < 2; ++mf)
#pragma unroll
        for (int e = 0; e < 4; ++e) {
            int t = mq * 32 + mf * 16 + (l >> 4) * 4 + e;
            float rd = rdnm[cb + t];
#pragma unroll
            for (int n = 0; n < 4; ++n) {
                int r = R0 + rg * 64 + n * 16 + (l & 15);
                float ov = b2f(qko[(cb + t) * 1536 + 1024 + r]);
                g[(cb + t) * DH + r] = f2b(ov * acc[mf][n][e] * rd);
            }
        }
}

extern "C" void kernel_launch(void* const* d_in, const int* in_sizes, int n_in,
                              void* d_out, int out_size, void* d_ws, size_t ws_size,
                              hipStream_t stream)
{
    (void)in_sizes; (void)n_in; (void)out_size; (void)ws_size;
    const float* x    = (const float*)d_in[0];
    const float* nw   = (const float*)d_in[1];
    const float* Wq   = (const float*)d_in[2];
    const float* Wk   = (const float*)d_in[3];
    const float* Wv   = (const float*)d_in[4];
    const float* wi   = (const float*)d_in[5];
    const float* wib  = (const float*)d_in[6];
    const float* wf   = (const float*)d_in[7];
    const float* wfb  = (const float*)d_in[8];
    const float* Wo   = (const float*)d_in[9];
    const float* bo   = (const float*)d_in[10];
    const float* Wout = (const float*)d_in[11];
    float* out = (float*)d_out;

    char* ws = (char*)d_ws;
    unsigned short* qko    = (unsigned short*)ws;                        // 0 .. 50,331,648
    unsigned short* kvT    = (unsigned short*)(ws + 50331648);           // v in rows 512+
    unsigned short* normed = (unsigned short*)(ws + 83886080);
    unsigned short* g      = normed;                                     // first 16 MB (normed dead)
    unsigned short* kw     = (unsigned short*)(ws + 100663296);
    float* Pbuf   = (float*)(ws + 117440512);
    float* aE     = (float*)(ws + 117964800);
    unsigned short* Wcat1  = (unsigned short*)(ws + 117440512);          // dead after gemm_qkv
    unsigned short* WvB    = (unsigned short*)(ws + 120586240);
    unsigned short* Woutb  = (unsigned short*)(ws + 122683392);
    float* zi     = (float*)(ws + 123731968);
    float* zf     = zi + MROWS;
    float* uarr   = zf + MROWS;
    float* aarr   = uarr + MROWS;
    float* rowsum = aarr + MROWS;
    float* rdnm   = rowsum + MROWS;

    // d_out as scratch until final gemm: Cchk (60 MiB) + stbuf (4 MiB)
    unsigned short* chk   = (unsigned short*)d_out;                      // 8*15*512*512*2
    unsigned short* stbuf = (unsigned short*)((char*)d_out + 62914560);  // 8*16*128*128*2

    norm_kernel    <<<MROWS, 256, 0, stream>>>(x, nw, wi, wf, wib, wfb, normed, zi, zf,
                                               Wq, Wk, Wo, Wv, Wout, Wcat1, WvB, Woutb);
    // QKO+V GEMM (blocks 0..2047) + mscan2 (blocks 2048..2055)
    gemm_qkv_ms    <<<2056, 256, 0, stream>>>(normed, Wcat1, WvB, DM, qko, bo,
                                              kvT + (size_t)512 * MROWS, zi, zf, uarr, aarr);
    // phaseA (256) + kwprep2 (1024) co-resident (R6 measured-best body)
    fusedA_kernel  <<<1280, 256, 0, stream>>>(qko, uarr, aarr, stbuf, rowsum, kw, Pbuf, aE);
    // C-scan + inline nhscan/denom epilogue
    cscan3_kernel  <<<512, 256, 0, stream>>>(kvT, kw, aE, chk, qko, Pbuf, aarr, rowsum, rdnm);
    // hout split to 512 blocks (2 blocks/CU)
    hout4_kernel   <<<512, 512, 0, stream>>>(qko, kvT, stbuf, chk, aarr, aE, rdnm, g);
    // A=g (16MB) >> B=Woutb (1MB): ORD=1, 1024 = exact round
    gemm_bt<1, 1>  <<<128 * 8, 256, 0, stream>>>(g, Woutb, MROWS, DM, DH, DM, nullptr, nullptr, out, x);
}

// Round 10
// 243.417 us; speedup vs baseline: 1.0321x; 1.0321x over previous
//
#include <hip/hip_runtime.h>
#include <cstdint>
#include <cmath>

#define T_SEQ 2048
#define NBATCH 8
#define DM 1024
#define DH 512
#define MROWS (NBATCH * T_SEQ)   // 16384
#define NC 16                    // chunks per batch
#define CL 128                   // chunk length

typedef short s8v __attribute__((ext_vector_type(8)));
typedef float f32x4 __attribute__((ext_vector_type(4)));

typedef unsigned int __attribute__((address_space(1))) uint_g;
typedef unsigned int __attribute__((address_space(3))) uint_l;

#define QKSCALE 0.044194173824159216f   // 1/sqrt(512)

__device__ __forceinline__ float b2f(unsigned short s) {
    union { unsigned u; float f; } c; c.u = ((unsigned)s) << 16; return c.f;
}
__device__ __forceinline__ unsigned short f2b(float f) {
    union { float f; unsigned u; } c; c.f = f;
    unsigned r = c.u + 0x7fffu + ((c.u >> 16) & 1u);
    return (unsigned short)(r >> 16);
}
__device__ __forceinline__ void gld_lds16(const void* g, void* l) {
    __builtin_amdgcn_global_load_lds((const uint_g*)g, (uint_l*)l, 16, 0, 0);
}

#define WAITV(N) asm volatile("s_waitcnt vmcnt(" #N ")" ::: "memory")
#define BARSYNC() do { asm volatile("" ::: "memory"); __builtin_amdgcn_s_barrier(); asm volatile("" ::: "memory"); } while (0)

// ---------------- RMSNorm + zi/zf + fused weight conversion ----------------
__global__ __launch_bounds__(256) void norm_kernel(
    const float* __restrict__ x, const float* __restrict__ nw,
    const float* __restrict__ wi, const float* __restrict__ wf,
    const float* __restrict__ wib, const float* __restrict__ wfb,
    unsigned short* __restrict__ normed, float* __restrict__ zi, float* __restrict__ zf,
    const float* __restrict__ Wq, const float* __restrict__ Wk,
    const float* __restrict__ Wo, const float* __restrict__ Wv,
    const float* __restrict__ Wout,
    unsigned short* __restrict__ Wcat1, unsigned short* __restrict__ WvB,
    unsigned short* __restrict__ Woutb)
{
    int t = blockIdx.x, tid = threadIdx.x;
    float4 xv = ((const float4*)(x + (size_t)t * DM))[tid];
    float ss = xv.x * xv.x + xv.y * xv.y + xv.z * xv.z + xv.w * xv.w;
#pragma unroll
    for (int m = 1; m < 64; m <<= 1) ss += __shfl_xor(ss, m, 64);
    __shared__ float sred[4];
    __shared__ float sred2[8];
    if ((tid & 63) == 0) sred[tid >> 6] = ss;
    __syncthreads();
    ss = sred[0] + sred[1] + sred[2] + sred[3];
    float rstd = rsqrtf(ss * (1.0f / DM) + 1e-6f);
    float4 nwv = ((const float4*)nw)[tid];
    float n0 = xv.x * rstd * nwv.x, n1 = xv.y * rstd * nwv.y;
    float n2 = xv.z * rstd * nwv.z, n3 = xv.w * rstd * nwv.w;
    ushort4 pk;
    pk.x = f2b(n0); pk.y = f2b(n1); pk.z = f2b(n2); pk.w = f2b(n3);
    ((ushort4*)(normed + (size_t)t * DM))[tid] = pk;
    float4 wiv = ((const float4*)wi)[tid];
    float4 wfv = ((const float4*)wf)[tid];
    float pzi = n0 * wiv.x + n1 * wiv.y + n2 * wiv.z + n3 * wiv.w;
    float pzf = n0 * wfv.x + n1 * wfv.y + n2 * wfv.z + n3 * wfv.w;
#pragma unroll
    for (int m = 1; m < 64; m <<= 1) {
        pzi += __shfl_xor(pzi, m, 64);
        pzf += __shfl_xor(pzf, m, 64);
    }
    if ((tid & 63) == 0) { sred2[tid >> 6] = pzi; sred2[4 + (tid >> 6)] = pzf; }
    __syncthreads();
    if (tid == 0) {
        zi[t] = sred2[0] + sred2[1] + sred2[2] + sred2[3] + wib[0];
        zf[t] = sred2[4] + sred2[5] + sred2[6] + sred2[7] + wfb[0];
    }
    // ---- fused weight conversion ----
    if (tid < 160) {
        int idx = blockIdx.x * 160 + tid;
        if (idx < 1572864) {
            int nrow = idx >> 10;
            float v;
            if      (nrow < 512)  v = Wq[idx];
            else if (nrow < 1024) v = Wk[idx - 512 * 1024];
            else                  v = Wo[idx - 1024 * 1024];
            Wcat1[idx] = f2b(v);
        } else if (idx < 2097152) {
            int j = idx - 1572864;
            WvB[j] = f2b(Wv[j]);
        } else {
            int j = idx - 2097152;
            Woutb[j] = f2b(Wout[j]);
        }
    }
}

// ---------------- merged QKO + V projection + mscan2 (blocks 2048+) ------
__global__ __launch_bounds__(256, 4) void gemm_qkv_ms(
    const unsigned short* __restrict__ normed, const unsigned short* __restrict__ Wcat1,
    const unsigned short* __restrict__ WvB, int K,
    unsigned short* __restrict__ qko, const float* __restrict__ bo,
    unsigned short* __restrict__ vout,
    const float* __restrict__ zi, const float* __restrict__ zf,
    float* __restrict__ u, float* __restrict__ a)
{
    __shared__ unsigned short As[128 * 64];
    __shared__ unsigned short Bs[128 * 64];
    __shared__ float wt[4];
    int tid = threadIdx.x;

    if (blockIdx.x >= 2048) {
        // ---- mscan2 body ----
        int b = blockIdx.x - 2048, lane = tid & 63, wid = tid >> 6;
        size_t base = (size_t)b * T_SEQ + tid * 8;
        float z_f[8], z_i[8];
        *(float4*)&z_f[0] = *(const float4*)&zf[base];
        *(float4*)&z_f[4] = *(const float4*)&zf[base + 4];
        *(float4*)&z_i[0] = *(const float4*)&zi[base];
        *(float4*)&z_i[4] = *(const float4*)&zi[base + 4];
        float c8[8]; float run = 0.0f;
#pragma unroll
        for (int i = 0; i < 8; ++i) { run += z_f[i]; c8[i] = run; }
        float v = run;
#pragma unroll
        for (int d = 1; d < 64; d <<= 1) {
            float o = __shfl_up(v, d, 64);
            if (lane >= d) v += o;
        }
        if (lane == 63) wt[wid] = v;
        __syncthreads();
        float woff = 0.0f;
        for (int j = 0; j < wid; ++j) woff += wt[j];
        float excl = __shfl_up(v, 1, 64);
        if (lane == 0) excl = 0.0f;
        float pre = woff + excl;
        float uu[8];
#pragma unroll
        for (int i = 0; i < 8; ++i) uu[i] = z_i[i] - (pre + c8[i]);
        *(float4*)&u[base] = *(float4*)&uu[0];
        *(float4*)&u[base + 4] = *(float4*)&uu[4];
        __syncthreads();
        float m8[8]; float rm = -INFINITY;
#pragma unroll
        for (int i = 0; i < 8; ++i) { rm = fmaxf(rm, uu[i]); m8[i] = rm; }
        float mv = rm;
#pragma unroll
        for (int d = 1; d < 64; d <<= 1) {
            float o = __shfl_up(mv, d, 64);
            if (lane >= d) mv = fmaxf(mv, o);
        }
        if (lane == 63) wt[wid] = mv;
        __syncthreads();
        float moff = -INFINITY;
        for (int j = 0; j < wid; ++j) moff = fmaxf(moff, wt[j]);
        float mexcl = __shfl_up(mv, 1, 64);
        if (lane == 0) mexcl = -INFINITY;
        float mpre = fmaxf(moff, mexcl);
        float aa[8];
#pragma unroll
        for (int i = 0; i < 8; ++i) aa[i] = fmaxf(mpre, m8[i]);
        *(float4*)&a[base] = *(float4*)&aa[0];
        *(float4*)&a[base + 4] = *(float4*)&aa[4];
        return;
    }

    // ---- GEMM body ----
    int l = tid & 63, w = tid >> 6;
    int wg = (blockIdx.x & 7) * 256 + (blockIdx.x >> 3);   // bijective, 2048 blocks
    int job = (wg >= 1536) ? 1 : 0;
    const unsigned short* A;
    const unsigned short* Bw;
    int bm, bn;
    if (job == 0) { A = normed; Bw = Wcat1; bn = wg % 12; bm = wg / 12; }
    else          { int w2 = wg - 1536; A = WvB; Bw = normed; bm = w2 & 3; bn = w2 >> 2; }
    int wr = w >> 1, wc = w & 1;
    f32x4 acc[4][4] = {};
    const size_t abase = (size_t)(bm * 128) * K;
    const size_t bbase = (size_t)(bn * 128) * K;

    for (int ks = 0; ks < K; ks += 64) {
        __syncthreads();
#pragma unroll
        for (int i = 0; i < 4; ++i) {
            int off = (i * 256 + tid) * 8;
            int row = off >> 6, kc = off & 63;
            int kcs = kc ^ ((row & 7) << 3);
            gld_lds16(A + abase + (size_t)row * K + ks + kcs, &As[off]);
            gld_lds16(Bw + bbase + (size_t)row * K + ks + kcs, &Bs[off]);
        }
        __syncthreads();
#pragma unroll
        for (int kk = 0; kk < 2; ++kk) {
            int cbo = kk * 32 + (l >> 4) * 8;
            s8v af[4], bfv[4];
#pragma unroll
            for (int m = 0; m < 4; ++m) {
                int row = wr * 64 + m * 16 + (l & 15);
                af[m] = *(const s8v*)&As[row * 64 + (cbo ^ ((row & 7) << 3))];
            }
#pragma unroll
            for (int n = 0; n < 4; ++n) {
                int row = wc * 64 + n * 16 + (l & 15);
                bfv[n] = *(const s8v*)&Bs[row * 64 + (cbo ^ ((row & 7) << 3))];
            }
#pragma unroll
            for (int m = 0; m < 4; ++m)
#pragma unroll
                for (int n = 0; n < 4; ++n)
                    acc[m][n] = __builtin_amdgcn_mfma_f32_16x16x32_bf16(af[m], bfv[n], acc[m][n], 0, 0, 0);
        }
    }

    if (job == 0) {
#pragma unroll
        for (int m = 0; m < 4; ++m) {
#pragma unroll
            for (int n = 0; n < 4; ++n) {
                int col = bn * 128 + wc * 64 + n * 16 + (l & 15);
#pragma unroll
                for (int r = 0; r < 4; ++r) {
                    int row = bm * 128 + wr * 64 + m * 16 + (l >> 4) * 4 + r;
                    float v = acc[m][n][r];
                    if (col < 1024) v *= QKSCALE;
                    else {
                        float s = v + bo[col - 1024];
                        v = 1.0f / (1.0f + expf(-s));
                    }
                    qko[(size_t)row * 1536 + col] = f2b(v);
                }
            }
        }
    } else {
#pragma unroll
        for (int m = 0; m < 4; ++m) {
#pragma unroll
            for (int n = 0; n < 4; ++n) {
                int col = bn * 128 + wc * 64 + n * 16 + (l & 15);
#pragma unroll
                for (int r = 0; r < 4; ++r) {
                    int row = bm * 128 + wr * 64 + m * 16 + (l >> 4) * 4 + r;
                    vout[(size_t)row * MROWS + col] = f2b(acc[m][n][r]);
                }
            }
        }
    }
}

// ---------------- 128x128 bf16 MFMA GEMM (output projection) -------------
template <int EPI, int ORD>
__global__ __launch_bounds__(256, 4) void gemm_bt(
    const unsigned short* __restrict__ A, const unsigned short* __restrict__ Bw,
    int M, int N, int K, int ldo,
    unsigned short* __restrict__ outb, const float* __restrict__ bo,
    float* __restrict__ outf, const float* __restrict__ xres)
{
    __shared__ unsigned short As[128 * 64];
    __shared__ unsigned short Bs[128 * 64];
    int tid = threadIdx.x;
    int l = tid & 63, w = tid >> 6;
    int cpx = gridDim.x >> 3;
    int wg = (blockIdx.x & 7) * cpx + (blockIdx.x >> 3);
    int mb = M >> 7;
    int nb = N >> 7;
    int bm, bn;
    if (ORD == 0) { bm = wg % mb; bn = wg / mb; }
    else          { bn = wg % nb; bm = wg / nb; }
    int wr = w >> 1, wc = w & 1;
    f32x4 acc[4][4] = {};
    const size_t abase = (size_t)(bm * 128) * K;
    const size_t bbase = (size_t)(bn * 128) * K;

    for (int ks = 0; ks < K; ks += 64) {
        __syncthreads();
#pragma unroll
        for (int i = 0; i < 4; ++i) {
            int off = (i * 256 + tid) * 8;
            int row = off >> 6, kc = off & 63;
            int kcs = kc ^ ((row & 7) << 3);
            gld_lds16(A + abase + (size_t)row * K + ks + kcs, &As[off]);
            gld_lds16(Bw + bbase + (size_t)row * K + ks + kcs, &Bs[off]);
        }
        __syncthreads();
#pragma unroll
        for (int kk = 0; kk < 2; ++kk) {
            int cbo = kk * 32 + (l >> 4) * 8;
            s8v af[4], bfv[4];
#pragma unroll
            for (int m = 0; m < 4; ++m) {
                int row = wr * 64 + m * 16 + (l & 15);
                af[m] = *(const s8v*)&As[row * 64 + (cbo ^ ((row & 7) << 3))];
            }
#pragma unroll
            for (int n = 0; n < 4; ++n) {
                int row = wc * 64 + n * 16 + (l & 15);
                bfv[n] = *(const s8v*)&Bs[row * 64 + (cbo ^ ((row & 7) << 3))];
            }
#pragma unroll
            for (int m = 0; m < 4; ++m)
#pragma unroll
                for (int n = 0; n < 4; ++n)
                    acc[m][n] = __builtin_amdgcn_mfma_f32_16x16x32_bf16(af[m], bfv[n], acc[m][n], 0, 0, 0);
        }
    }

#pragma unroll
    for (int m = 0; m < 4; ++m) {
#pragma unroll
        for (int n = 0; n < 4; ++n) {
            int col = bn * 128 + wc * 64 + n * 16 + (l & 15);
#pragma unroll
            for (int r = 0; r < 4; ++r) {
                int row = bm * 128 + wr * 64 + m * 16 + (l >> 4) * 4 + r;
                float v = acc[m][n][r];
                if (EPI == 3) {
                    outb[(size_t)row * ldo + col] = f2b(v);
                } else {
                    size_t idx = (size_t)row * ldo + col;
                    outf[idx] = xres[idx] + v;
                }
            }
        }
    }
}

// ---------------- fusedA: phaseA (blocks 0..255) + kwprep2 (256..1279) ----
__global__ __launch_bounds__(256) void fusedA_kernel(
    const unsigned short* __restrict__ qko,
    const float* __restrict__ u, const float* __restrict__ a,
    unsigned short* __restrict__ stb, float* __restrict__ rowsum,
    unsigned short* __restrict__ kw, float* __restrict__ P, float* __restrict__ aE)
{
    __shared__ char smem[17920];
    int bid = blockIdx.x, tid = threadIdx.x;

    if (bid < 256) {
        // ---- phaseA: St[t][j] = exp(u_j - a_t)*(q_t.k_j), j<=t ----
        unsigned short* Qs = (unsigned short*)smem;            // 64*32
        unsigned short* Ks = (unsigned short*)(smem + 4096);   // 128*32
        int b = bid & 7, c = (bid >> 3) & 15, th = bid >> 7;
        int l = tid & 63, wv = tid >> 6;
        size_t cb = (size_t)b * T_SEQ + c * CL;
        f32x4 acc[8] = {};
        for (int ks = 0; ks < 512; ks += 32) {
            __syncthreads();
            {
                int p = tid;
                int row = p >> 2, kc = (p & 3) * 8;
                gld_lds16(qko + (cb + th * 64 + row) * 1536 + ks + kc, &Qs[p * 8]);
#pragma unroll
                for (int rI = 0; rI < 2; ++rI) {
                    int pp = rI * 256 + tid;
                    int rw = pp >> 2, kk = (pp & 3) * 8;
                    gld_lds16(qko + (cb + rw) * 1536 + 512 + ks + kk, &Ks[pp * 8]);
                }
            }
            __syncthreads();
            s8v af = *(const s8v*)&Qs[(wv * 16 + (l & 15)) * 32 + (l >> 4) * 8];
#pragma unroll
            for (int n = 0; n < 8; ++n) {
                s8v bf = *(const s8v*)&Ks[(n * 16 + (l & 15)) * 32 + (l >> 4) * 8];
                acc[n] = __builtin_amdgcn_mfma_f32_16x16x32_bf16(af, bf, acc[n], 0, 0, 0);
            }
        }
        float rs[4] = {0.f, 0.f, 0.f, 0.f};
        size_t stbase = (size_t)(b * NC + c) * (CL * CL);
#pragma unroll
        for (int e = 0; e < 4; ++e) {
            int tl = th * 64 + wv * 16 + (l >> 4) * 4 + e;
            float a_t = a[cb + tl];
#pragma unroll
            for (int n = 0; n < 8; ++n) {
                int j = n * 16 + (l & 15);
                float val = (j <= tl) ? acc[n][e] * expf(u[cb + j] - a_t) : 0.0f;
                rs[e] += val;
                stb[stbase + (size_t)tl * CL + j] = f2b(val);
            }
        }
#pragma unroll
        for (int e = 0; e < 4; ++e) {
#pragma unroll
            for (int m = 1; m < 16; m <<= 1) rs[e] += __shfl_xor(rs[e], m, 64);
        }
        if ((l & 15) == 0) {
#pragma unroll
            for (int e = 0; e < 4; ++e)
                rowsum[cb + th * 64 + wv * 16 + (l >> 4) * 4 + e] = rs[e];
        }
    } else {
        // ---- kwprep2: transpose k + scale; P row-sums ----
        unsigned short (*T)[136] = (unsigned short(*)[136])smem;   // 64*136
        float* w_l = (float*)(smem + 17408);                       // CL floats
        int kb = bid - 256;
        int b = kb & 7, c = (kb >> 3) & 15, stt = kb >> 7;   // stt: 0..7
        int s0 = stt * 64;
        size_t cb = (size_t)b * T_SEQ + c * CL;
        float a_e = a[cb + CL - 1];
        if (tid < CL) w_l[tid] = expf(u[cb + tid] - a_e);
        if (tid == 0 && stt == 0) aE[b * NC + c] = a_e;
#pragma unroll
        for (int it = 0; it < 4; ++it) {
            int flat = it * 256 + tid;          // 0..1023
            int t = flat >> 3, g = flat & 7;
            s8v v = *(const s8v*)&qko[(cb + t) * 1536 + 512 + s0 + g * 8];
#pragma unroll
            for (int e = 0; e < 8; ++e) T[g * 8 + e][t] = (unsigned short)v[e];
        }
        __syncthreads();
        int s = tid >> 2, tg = tid & 3;
        float psum = 0.0f;
#pragma unroll
        for (int j = 0; j < 4; ++j) {
            int t0 = tg * 32 + j * 8;
            s8v kv = *(const s8v*)&T[s][t0];
            s8v kwv;
#pragma unroll
            for (int e = 0; e < 8; ++e) {
                float f = b2f((unsigned short)kv[e]) * w_l[t0 + e];
                kwv[e] = (short)f2b(f);
                psum += f;
            }
            *(s8v*)&kw[(size_t)(s0 + s) * MROWS + cb + t0] = kwv;
        }
        psum += __shfl_xor(psum, 1, 64);
        psum += __shfl_xor(psum, 2, 64);
        if (tg == 0) P[(size_t)(b * NC + c) * 512 + s0 + s] = psum;
    }
}

// ---------------- cscan3: C checkpoints + fused denom/nhscan epilogue ----
__global__ __launch_bounds__(256, 2) void cscan3_kernel(
    const unsigned short* __restrict__ kvT, const unsigned short* __restrict__ kw,
    const float* __restrict__ aE, unsigned short* __restrict__ chk,
    const unsigned short* __restrict__ qko, const float* __restrict__ P,
    const float* __restrict__ a, const float* __restrict__ rowsum,
    float* __restrict__ rdnm)
{
    __shared__ unsigned short Vs[2][64 * 128];
    __shared__ unsigned short Ks[2][64 * 128];
    int bid = blockIdx.x;
    int b = bid & 7, rt = (bid >> 3) & 7, st = bid >> 6;   // 8 x 8 x 8
    int r0 = rt * 64, s0 = st * 64;
    int tid = threadIdx.x, l = tid & 63;
    int w = tid >> 6, wr = w >> 1, wc = w & 1;
    size_t tb = (size_t)b * T_SEQ;
    int srow = tid >> 4, sg = tid & 15;
    f32x4 acc[2][2] = {};
    float a_prev = 0.0f;

#define CSTAGE(c, buf) do { \
        size_t cb_ = tb + (size_t)(c) * CL; \
        _Pragma("unroll") \
        for (int i = 0; i < 4; ++i) { \
            int row_ = i * 16 + srow; \
            int gs_ = sg ^ (row_ & 7); \
            gld_lds16(kvT + (size_t)(512 + r0 + row_) * MROWS + cb_ + gs_ * 8, \
                      &Vs[buf][(i * 256 + tid) * 8]); \
        } \
        _Pragma("unroll") \
        for (int i = 0; i < 4; ++i) { \
            int row_ = i * 16 + srow; \
            int gs_ = sg ^ (row_ & 7); \
            gld_lds16(kw + (size_t)(s0 + row_) * MROWS + cb_ + gs_ * 8, \
                      &Ks[buf][(i * 256 + tid) * 8]); \
        } } while (0)

    CSTAGE(0, 0);
    for (int c = 0; c < NC; ++c) {
        int cur = c & 1;
        if (c + 1 < NC) { CSTAGE(c + 1, cur ^ 1); WAITV(8); }
        else            { WAITV(0); }
        BARSYNC();
        float a_e = aE[b * NC + c];
        if (c > 0) {
            unsigned short* slot = chk + (size_t)(b * (NC - 1) + (c - 1)) * (512 * 512);
#pragma unroll
            for (int m = 0; m < 2; ++m)
#pragma unroll
                for (int n = 0; n < 2; ++n)
#pragma unroll
                    for (int e = 0; e < 4; ++e) {
                        int r = r0 + wr * 32 + m * 16 + (l >> 4) * 4 + e;
                        int s = s0 + wc * 32 + n * 16 + (l & 15);
                        slot[r * 512 + s] = f2b(acc[m][n][e]);
                    }
            float gam = expf(a_prev - a_e);
#pragma unroll
            for (int m = 0; m < 2; ++m)
#pragma unroll
                for (int n = 0; n < 2; ++n)
#pragma unroll
                    for (int e = 0; e < 4; ++e) acc[m][n][e] *= gam;
        }
#pragma unroll
        for (int ks = 0; ks < 4; ++ks) {
            s8v vf[2], kf[2];
#pragma unroll
            for (int m = 0; m < 2; ++m) {
                int row = wr * 32 + m * 16 + (l & 15);
                int gf = ks * 4 + (l >> 4);
                vf[m] = *(const s8v*)&Vs[cur][row * 128 + ((gf ^ (row & 7)) << 3)];
            }
#pragma unroll
            for (int n = 0; n < 2; ++n) {
                int row = wc * 32 + n * 16 + (l & 15);
                int gf = ks * 4 + (l >> 4);
                kf[n] = *(const s8v*)&Ks[cur][row * 128 + ((gf ^ (row & 7)) << 3)];
            }
#pragma unroll
            for (int m = 0; m < 2; ++m)
#pragma unroll
                for (int n = 0; n < 2; ++n)
                    acc[m][n] = __builtin_amdgcn_mfma_f32_16x16x32_bf16(vf[m], kf[n], acc[m][n], 0, 0, 0);
        }
        a_prev = a_e;
        BARSYNC();
    }
#undef CSTAGE

    // ---- fused denom (nhscan inline): 32 t's per block, 8 per wave ----
    {
        int wv = tid >> 6;
        int t0 = bid * 32 + wv * 8;
        int bt = t0 >> 11, ct = (t0 & 2047) >> 7;
        float nh[8] = {0, 0, 0, 0, 0, 0, 0, 0};
        float aprev = 0.0f;
        for (int cp = 0; cp < ct; ++cp) {
            float ae = aE[bt * NC + cp];
            float gam = (cp == 0) ? 0.0f : expf(aprev - ae);
            const float* Pp = P + (size_t)(bt * NC + cp) * 512 + l * 8;
            float4 p0 = *(const float4*)Pp;
            float4 p1 = *(const float4*)(Pp + 4);
#pragma unroll
            for (int e = 0; e < 8; ++e) nh[e] *= gam;
            nh[0] += p0.x; nh[1] += p0.y; nh[2] += p0.z; nh[3] += p0.w;
            nh[4] += p1.x; nh[5] += p1.y; nh[6] += p1.z; nh[7] += p1.w;
            aprev = ae;
        }
        float aeprev = (ct > 0) ? aE[bt * NC + ct - 1] : 0.0f;
        for (int tt = 0; tt < 8; ++tt) {
            int tc = t0 + tt;
            s8v qv = *(const s8v*)(qko + (size_t)tc * 1536 + l * 8);
            float nq = 0.0f;
#pragma unroll
            for (int e = 0; e < 8; ++e) nq += b2f((unsigned short)qv[e]) * nh[e];
#pragma unroll
            for (int m = 1; m < 64; m <<= 1) nq += __shfl_xor(nq, m, 64);
            if (l == 0) {
                float beta = (ct == 0) ? 0.0f : expf(aeprev - a[tc]);
                rdnm[tc] = 1.0f / fmaxf(fabsf(beta * nq + rowsum[tc]), 1.0f);
            }
        }
    }
}

// ---------------- hout2: G = beta*(Q.Cchk^T) + St.V ; h = o*G*rdnm --------
__global__ __launch_bounds__(512) void hout2_kernel(
    const unsigned short* __restrict__ qko, const unsigned short* __restrict__ kvT,
    const unsigned short* __restrict__ st, const unsigned short* __restrict__ chk,
    const float* __restrict__ a, const float* __restrict__ aE,
    const float* __restrict__ rdnm, unsigned short* __restrict__ g)
{
    __shared__ unsigned short Bsh[2][256 * 64];
    int bid = blockIdx.x;
    int b = bid & 7, cc = bid >> 3;
    int c = cc >> 1, rh = cc & 1;
    int tid = threadIdx.x, l = tid & 63, wv = tid >> 6;
    int mq = wv & 3, rg = wv >> 2;
    int rr = rg * 128 + rh * 256;
    int R0 = rh * 256;
    size_t cb = (size_t)b * T_SEQ + c * CL;
    f32x4 acc[2][8] = {};

    int srow7 = tid >> 3;        // 0..63 (row within 64-row group)
    int sgc = tid & 7;

    if (c > 0) {
        const unsigned short* slot = chk + (size_t)(b * (NC - 1) + (c - 1)) * (512 * 512);
#define HSTG_C(ksb, buf) do { \
        _Pragma("unroll") \
        for (int i = 0; i < 4; ++i) { \
            int row_ = i * 64 + srow7; \
            int gs_ = sgc ^ (row_ & 7); \
            gld_lds16(slot + (size_t)(R0 + row_) * 512 + (ksb) * 64 + gs_ * 8, \
                      &Bsh[buf][(i * 512 + tid) * 8]); \
        } } while (0)
        HSTG_C(0, 0);
        for (int s = 0; s < 8; ++s) {
            int cur = s & 1;
            if (s + 1 < 8) { HSTG_C(s + 1, cur ^ 1); WAITV(4); }
            else           { WAITV(0); }
            BARSYNC();
#pragma unroll
            for (int kk = 0; kk < 2; ++kk) {
                s8v aq[2];
#pragma unroll
                for (int mf = 0; mf < 2; ++mf)
                    aq[mf] = *(const s8v*)&qko[(cb + mq * 32 + mf * 16 + (l & 15)) * 1536 + s * 64 + kk * 32 + (l >> 4) * 8];
#pragma unroll
                for (int n = 0; n < 8; ++n) {
                    int row = rg * 128 + n * 16 + (l & 15);
                    int gr = (kk * 4 + (l >> 4)) ^ (row & 7);
                    s8v bc = *(const s8v*)&Bsh[cur][row * 64 + gr * 8];
                    acc[0][n] = __builtin_amdgcn_mfma_f32_16x16x32_bf16(aq[0], bc, acc[0][n], 0, 0, 0);
                    acc[1][n] = __builtin_amdgcn_mfma_f32_16x16x32_bf16(aq[1], bc, acc[1][n], 0, 0, 0);
                }
            }
            BARSYNC();
        }
#undef HSTG_C
        float aprev = aE[b * NC + c - 1];
#pragma unroll
        for (int mf = 0; mf < 2; ++mf)
#pragma unroll
            for (int e = 0; e < 4; ++e) {
                int t = mq * 32 + mf * 16 + (l >> 4) * 4 + e;
                float bta = expf(aprev - a[cb + t]);
#pragma unroll
                for (int n = 0; n < 8; ++n) acc[mf][n][e] *= bta;
            }
    }

    // ---- St.V phase: V tile [256 r][64 t-cols], 2 steps ----
    const unsigned short* stp = st + (size_t)(b * NC + c) * (CL * CL);
#define HSTG_V(vsb, buf) do { \
        _Pragma("unroll") \
        for (int i = 0; i < 4; ++i) { \
            int row_ = i * 64 + srow7; \
            int gs_ = sgc ^ (row_ & 7); \
            gld_lds16(kvT + (size_t)(512 + R0 + row_) * MROWS + cb + (vsb) * 64 + gs_ * 8, \
                      &Bsh[buf][(i * 512 + tid) * 8]); \
        } } while (0)
    HSTG_V(0, 0);
    for (int s = 0; s < 2; ++s) {
        if (s + 1 < 2) { HSTG_V(1, 1); WAITV(4); }
        else           { WAITV(0); }
        BARSYNC();
#pragma unroll
        for (int kk = 0; kk < 2; ++kk) {
            s8v aq[2];
#pragma unroll
            for (int mf = 0; mf < 2; ++mf)
                aq[mf] = *(const s8v*)&stp[(size_t)(mq * 32 + mf * 16 + (l & 15)) * CL + s * 64 + kk * 32 + (l >> 4) * 8];
#pragma unroll
            for (int n = 0; n < 8; ++n) {
                int row = rg * 128 + n * 16 + (l & 15);
                int gr = (kk * 4 + (l >> 4)) ^ (row & 7);
                s8v bv = *(const s8v*)&Bsh[s][row * 64 + gr * 8];
                acc[0][n] = __builtin_amdgcn_mfma_f32_16x16x32_bf16(aq[0], bv, acc[0][n], 0, 0, 0);
                acc[1][n] = __builtin_amdgcn_mfma_f32_16x16x32_bf16(aq[1], bv, acc[1][n], 0, 0, 0);
            }
        }
        BARSYNC();
    }
#undef HSTG_V

#pragma unroll
    for (int mf = 0; mf < 2; ++mf)
#pragma unroll
        for (int e = 0; e < 4; ++e) {
            int t = mq * 32 + mf * 16 + (l >> 4) * 4 + e;
            float rd = rdnm[cb + t];
#pragma unroll
            for (int n = 0; n < 8; ++n) {
                int r = rr + n * 16 + (l & 15);
                float ov = b2f(qko[(cb + t) * 1536 + 1024 + r]);
                g[(cb + t) * DH + r] = f2b(ov * acc[mf][n][e] * rd);
            }
        }
}

extern "C" void kernel_launch(void* const* d_in, const int* in_sizes, int n_in,
                              void* d_out, int out_size, void* d_ws, size_t ws_size,
                              hipStream_t stream)
{
    (void)in_sizes; (void)n_in; (void)out_size; (void)ws_size;
    const float* x    = (const float*)d_in[0];
    const float* nw   = (const float*)d_in[1];
    const float* Wq   = (const float*)d_in[2];
    const float* Wk   = (const float*)d_in[3];
    const float* Wv   = (const float*)d_in[4];
    const float* wi   = (const float*)d_in[5];
    const float* wib  = (const float*)d_in[6];
    const float* wf   = (const float*)d_in[7];
    const float* wfb  = (const float*)d_in[8];
    const float* Wo   = (const float*)d_in[9];
    const float* bo   = (const float*)d_in[10];
    const float* Wout = (const float*)d_in[11];
    float* out = (float*)d_out;

    char* ws = (char*)d_ws;
    unsigned short* qko    = (unsigned short*)ws;                        // 0 .. 50,331,648
    unsigned short* kvT    = (unsigned short*)(ws + 50331648);           // v in rows 512+
    unsigned short* normed = (unsigned short*)(ws + 83886080);
    unsigned short* g      = normed;                                     // first 16 MB (normed dead)
    unsigned short* kw     = (unsigned short*)(ws + 100663296);
    float* Pbuf   = (float*)(ws + 117440512);
    float* aE     = (float*)(ws + 117964800);
    unsigned short* Wcat1  = (unsigned short*)(ws + 117440512);          // dead after gemm_qkv
    unsigned short* WvB    = (unsigned short*)(ws + 120586240);
    unsigned short* Woutb  = (unsigned short*)(ws + 122683392);
    float* zi     = (float*)(ws + 123731968);
    float* zf     = zi + MROWS;
    float* uarr   = zf + MROWS;
    float* aarr   = uarr + MROWS;
    float* rowsum = aarr + MROWS;
    float* rdnm   = rowsum + MROWS;

    // d_out as scratch until final gemm: Cchk (60 MiB) + stbuf (4 MiB)
    unsigned short* chk   = (unsigned short*)d_out;                      // 8*15*512*512*2
    unsigned short* stbuf = (unsigned short*)((char*)d_out + 62914560);  // 8*16*128*128*2

    norm_kernel    <<<MROWS, 256, 0, stream>>>(x, nw, wi, wf, wib, wfb, normed, zi, zf,
                                               Wq, Wk, Wo, Wv, Wout, Wcat1, WvB, Woutb);
    // QKO+V GEMM (blocks 0..2047) + mscan2 (blocks 2048..2055)
    gemm_qkv_ms    <<<2056, 256, 0, stream>>>(normed, Wcat1, WvB, DM, qko, bo,
                                              kvT + (size_t)512 * MROWS, zi, zf, uarr, aarr);
    // phaseA (256) + kwprep2 (1024) co-resident
    fusedA_kernel  <<<1280, 256, 0, stream>>>(qko, uarr, aarr, stbuf, rowsum, kw, Pbuf, aE);
    // C-scan + inline nhscan/denom epilogue
    cscan3_kernel  <<<512, 256, 0, stream>>>(kvT, kw, aE, chk, qko, Pbuf, aarr, rowsum, rdnm);
    hout2_kernel   <<<256, 512, 0, stream>>>(qko, kvT, stbuf, chk, aarr, aE, rdnm, g);
    // A=g (16MB) >> B=Woutb (1MB): ORD=1, 1024 = exact round
    gemm_bt<1, 1>  <<<128 * 8, 256, 0, stream>>>(g, Woutb, MROWS, DM, DH, DM, nullptr, nullptr, out, x);
}